// Round 14
// baseline (132.327 us; speedup 1.0000x reference)
//
#include <hip/hip_runtime.h>
#include <hip/hip_bf16.h>
#include <math.h>

#define BB 64
#define PP 10
#define SS 64
#define KK 32
#define HH 128
#define NN 33          // KK+1
#define TOTAL (BB*KK)  // 2048
#define G3 384         // 3*HH

// workspace layout (in floats)
// W_msg repack: wpos[2][128] | wa4[32][128][4] | wj4[32][128][4]
#define WPOS_OFF 0
#define WA4_OFF  256
#define WJ4_OFF  (256 + 16384)
#define WT_SZ    33024
#define U_OFF  WT_SZ
#define UV_SZ  (BB*NN*HH)
#define V_OFF  (U_OFF + UV_SZ)
#define OS_OFF (V_OFF + UV_SZ)

// seq_start_end may arrive as int32 (x64 off) or int64 (x64 on).
__device__ inline void get_se(const int* __restrict__ sse, int b, int& start, int& endv) {
    if (sse[1] == 0) { start = sse[4 * b]; endv = sse[4 * b + 2]; }   // int64
    else             { start = sse[2 * b]; endv = sse[2 * b + 1]; }   // int32
}

// ---------------- K0: repack W_msg (128x258) ----------------
__global__ __launch_bounds__(256) void k0_repack(const float* __restrict__ Wmsg,
                                                 float* __restrict__ wt) {
    int idx = blockIdx.x * 256 + threadIdx.x;
    if (idx < 256) {
        int c = idx >> 7, h = idx & 127;
        wt[WPOS_OFF + idx] = Wmsg[h * 258 + c];
    } else if (idx < WT_SZ) {
        int j = idx - 256;
        int reg = j >> 14;            // 0 -> wa4, 1 -> wj4
        int jj = j & 16383;
        int c4 = jj >> 9, rem = jj & 511, h = rem >> 2, i = rem & 3;
        int col = (reg ? 130 : 2) + 4 * c4 + i;
        wt[256 + j] = Wmsg[h * 258 + col];
    }
}

// ---------------- K1: u[b,a,h], v[b,a,h] ----------------
// R13-validated: LDS-staged ctx rows, 704 blocks for latency hiding.
__global__ __launch_bounds__(256) void k1_uv(
    const float* __restrict__ agent_ctx, const float* __restrict__ ngh_pos,
    const float* __restrict__ ngh_ctx, const int* __restrict__ sse,
    const float* __restrict__ bmsg, const float* __restrict__ wt,
    float* __restrict__ ws)
{
    int b = blockIdx.x / 11, tile = blockIdx.x % 11;
    int a0 = tile * 3;                // 33 = 11 * 3
    int t = threadIdx.x;
    int h = t & 127, half = t >> 7;   // waves 0,1 -> u ; waves 2,3 -> v
    int start, endv;
    get_se(sse, b, start, endv);

    __shared__ __align__(16) float ctx_s[3][HH];   // 1.5 KB
    __shared__ float pxy_s[3][2];

    if (t < 96) {                     // stage 3 ctx rows, coalesced float4
        int i = t >> 5, c = t & 31;
        int a = a0 + i;
        const float* src;
        if (a == 0) src = agent_ctx + (size_t)b * HH;
        else {
            int ic = min(max(start + a - 1, 0), TOTAL - 1);
            src = ngh_ctx + (size_t)ic * HH;
        }
        ((float4*)&ctx_s[i][0])[c] = ((const float4*)src)[c];
    }
    if (t < 3) {
        int a = a0 + t;
        float px = 0.f, py = 0.f;
        if (a > 0) {
            int ic = min(max(start + a - 1, 0), TOTAL - 1);
            px = ngh_pos[ic * 2]; py = ngh_pos[ic * 2 + 1];
        }
        pxy_s[t][0] = px; pxy_s[t][1] = py;
    }
    __syncthreads();

    const float4* w4base = (const float4*)(wt + (half ? WJ4_OFF : WA4_OFF));
    float acc[3] = {0.f, 0.f, 0.f};
    for (int c4 = 0; c4 < 32; c4++) {
        float4 w4 = w4base[c4 * 128 + h];              // coalesced 16B/lane (L2)
        #pragma unroll
        for (int i = 0; i < 3; i++) {
            float4 cv = ((const float4*)&ctx_s[i][0])[c4];  // LDS broadcast, free
            acc[i] += w4.x * cv.x + w4.y * cv.y + w4.z * cv.z + w4.w * cv.w;
        }
    }
    float wp0 = wt[WPOS_OFF + h], wp1 = wt[WPOS_OFF + 128 + h];
    float bm = bmsg[h];
    float* uout = ws + U_OFF;
    float* vout = ws + V_OFF;
    #pragma unroll
    for (int i = 0; i < 3; i++) {
        int a = a0 + i;
        float pt = pxy_s[i][0] * wp0 + pxy_s[i][1] * wp1;
        if (half == 0) uout[(b * NN + a) * HH + h] = acc[i] - pt;
        else           vout[(b * NN + a) * HH + h] = acc[i] + pt + bm;
    }
}

// ---------------- K3: u/v -> pooled (in LDS) -> gi/gh -> GRU -> per-b sum ----
// R14: k2 folded in. Stage u[33][128], v[33][128], ctx[32][128]; compute
// pooled IN-PLACE over u rows 1..32 (each slot read+written by exactly one
// thread; v read-only). ~17 MFLOP x8 hc-dup ~= 2 us chip-wide. Kills the
// pooled HBM/L2 round-trip, k2's 33x re-read pattern, and one launch.
// LDS = 63 KB (<= 64 KB static limit), 2 blocks/CU.
__global__ __launch_bounds__(384) void k3_gru(
    const float* __restrict__ ws_u, const float* __restrict__ ws_v,
    const float* __restrict__ ngh_ctx, const int* __restrict__ sse,
    const float* __restrict__ Wih, const float* __restrict__ Whh,
    const float* __restrict__ bih, const float* __restrict__ bhh,
    float* __restrict__ outsum)
{
    int b = blockIdx.x >> 3, hc = blockIdx.x & 7;
    int t = threadIdx.x;
    __shared__ __align__(16) float u_s[NN][HH];      // 16.5 KB; rows 1..32 -> pooled
    __shared__ __align__(16) float v_s[NN][HH];      // 16.5 KB
    __shared__ __align__(16) float ctx_s[KK][HH];    // 16 KB
    __shared__ float gi_s[KK][48];                   // 6 KB
    __shared__ float gh_s[KK][48];                   // 6 KB
    __shared__ float hn_s[KK * 16];                  // 2 KB
    int start, endv;
    get_se(sse, b, start, endv);

    // ---- stage u, v, ctx into LDS (coalesced float4) ----
    {
        const float4* us = (const float4*)(ws_u + (size_t)b * NN * HH);
        const float4* vs = (const float4*)(ws_v + (size_t)b * NN * HH);
        float4* ud = (float4*)&u_s[0][0];
        float4* vd = (float4*)&v_s[0][0];
        for (int i = t; i < NN * 32; i += 384) { ud[i] = us[i]; vd[i] = vs[i]; }
        float4* cd = (float4*)&ctx_s[0][0];
        for (int i = t; i < KK * 32; i += 384) {
            int n = i >> 5, c = i & 31;
            int ic = min(max(start + n, 0), TOTAL - 1);
            cd[i] = ((const float4*)(ngh_ctx + (size_t)ic * HH))[c];
        }
    }
    __syncthreads();

    // ---- pooled in-place: u_s[n+1][h] <- sum_{j != n+1} relu(u+v[j]) ----
    // Lanes read consecutive h per instruction -> 2-way LDS aliasing (free).
    for (int it = t; it < KK * HH; it += 384) {
        int n = it >> 7, h = it & 127;
        float uval = u_s[n + 1][h];
        float s = 0.f;
        #pragma unroll 11
        for (int j = 0; j < NN; j++) s += fmaxf(uval + v_s[j][h], 0.f);
        s -= fmaxf(uval + v_s[n + 1][h], 0.f);   // remove diagonal
        u_s[n + 1][h] = s;
    }
    __syncthreads();

    bool is_gh = (t >= 192);
    int r4 = is_gh ? (t - 192) : t;     // 0..191
    int row = r4 >> 2;                  // 0..47
    int q   = r4 & 3;                   // quarter of the 128-d dot
    int grow = (row >> 4) * HH + hc * 16 + (row & 15);

    // weights in rotated chunk order matching the LDS read rotation
    const float4* Wr = (const float4*)((is_gh ? Whh : Wih) + (size_t)grow * HH);
    float4 w[8];
    int cidx[8];
    #pragma unroll
    for (int s = 0; s < 8; s++) {
        int idx = (s + 2 * q) & 7;      // bank set (idx*4)%32: distinct per q
        cidx[s] = q * 8 + idx;
        w[s] = Wr[cidx[s]];
    }
    float bias = is_gh ? bhh[grow] : bih[grow];

    const float4* vecbase = is_gh ? (const float4*)&ctx_s[0][0]
                                  : (const float4*)&u_s[1][0];   // pooled rows
    for (int n = 0; n < KK; n++) {
        const float4* vp = vecbase + n * 32;
        float d = 0.f;
        #pragma unroll
        for (int s = 0; s < 8; s++) {
            float4 v = vp[cidx[s]];
            d += w[s].x * v.x + w[s].y * v.y + w[s].z * v.z + w[s].w * v.w;
        }
        d += __shfl_xor(d, 1);          // combine quarters (lane-quads)
        d += __shfl_xor(d, 2);
        if (q == 0) {
            if (is_gh) gh_s[n][row] = d + bias;
            else       gi_s[n][row] = d + bias;
        }
    }
    __syncthreads();
    for (int it = t; it < KK * 16; it += 384) {   // 512 GRU items, parallel
        int n = it >> 4, h = it & 15;
        float ir = gi_s[n][h], iz = gi_s[n][16 + h], inn = gi_s[n][32 + h];
        float hr = gh_s[n][h], hz = gh_s[n][16 + h], hnn = gh_s[n][32 + h];
        float cval = ctx_s[n][hc * 16 + h];
        float r = 1.f / (1.f + expf(-(ir + hr)));
        float z = 1.f / (1.f + expf(-(iz + hz)));
        float nn = tanhf(inn + r * hnn);
        hn_s[it] = (1.f - z) * nn + z * cval;
    }
    __syncthreads();
    if (t < 16) {
        float s = 0.f;
        #pragma unroll
        for (int n = 0; n < KK; n++) s += hn_s[n * 16 + t];
        outsum[b * HH + hc * 16 + t] = s;
    }
}

// ---------------- K4: validity, output assembly, lane_recon, slow path ----------------
__global__ __launch_bounds__(128) void k4_out(
    const float* __restrict__ lanes_in, const float* __restrict__ ngh_pos,
    const float* __restrict__ lane_ctx, const int* __restrict__ sse,
    const unsigned char* __restrict__ vn8, const int* __restrict__ vn32,
    const float* __restrict__ ws_u, const float* __restrict__ ws_v,
    const float* __restrict__ outsum, const float* __restrict__ ngh_ctx,
    const float* __restrict__ Wih, const float* __restrict__ Whh,
    const float* __restrict__ bih, const float* __restrict__ bhh,
    float* __restrict__ out)
{
    int bp = blockIdx.x;
    int b = bp / PP;
    int t = threadIdx.x;
    __shared__ float lane_s[SS][2];
    __shared__ float mins[4][KK];
    __shared__ int vf_s[KK];
    __shared__ int nan_s, ninv_s;
    __shared__ float pool_s[HH], ctx_s[HH], gi_s[G3], gh_s[G3];

    if (t == 0) nan_s = 0;
    __syncthreads();
    {
        int s = t >> 1, c = t & 1;
        float v = lanes_in[(s * (BB * PP) + bp) * 2 + c];
        lane_s[s][c] = v;
        if (isnan(v)) atomicOr(&nan_s, 1);
    }
    __syncthreads();
    bool lnan = nan_s != 0;
    int start, endv;
    get_se(sse, b, start, endv);
    bool vnb = (vn8[b] != 0) || (vn32[b] != 0);
    {
        int k = t & 31, sh = t >> 5;
        int ic = min(max(start + k, 0), TOTAL - 1);
        float nx = ngh_pos[ic * 2], ny = ngh_pos[ic * 2 + 1];
        float m;
        if (lnan) m = nx * nx + ny * ny;
        else {
            m = 3.4e38f;
            for (int s = sh * 16; s < sh * 16 + 16; s++) {
                float dx = nx - lane_s[s][0], dy = ny - lane_s[s][1];
                m = fminf(m, dx * dx + dy * dy);
            }
        }
        mins[sh][k] = m;
    }
    __syncthreads();
    if (t < KK) {
        float m = fminf(fminf(mins[0][t], mins[1][t]), fminf(mins[2][t], mins[3][t]));
        bool mask = (start + t) < endv;
        bool valid = (m < 25.0f) && mask && vnb;
        vf_s[t] = valid ? 1 : 0;
    }
    __syncthreads();
    if (t == 0) {
        int c = 0;
        for (int k2 = 0; k2 < KK; k2++) c += 1 - vf_s[k2];
        ninv_s = c;
    }
    out[bp * HH + t] = lane_ctx[bp * HH + t];
    __syncthreads();

    float* out2 = out + BB * PP * HH;
    if (ninv_s == 0) {
        out2[bp * HH + t] = outsum[b * HH + t];
        return;
    }
    // slow path (correctness only; not hit on this data): pooled recomputed
    // directly from u/v with the validity mask (pooled no longer materialized).
    float acc = 0.f;
    const float* ub = ws_u + b * NN * HH;
    const float* vb = ws_v + b * NN * HH;
    for (int am1 = 0; am1 < KK; am1++) {
        if (!vf_s[am1]) continue;
        int a = am1 + 1;
        {
            float uval = ub[a * HH + t];
            float pc = 0.f;
            for (int j = 0; j < NN; j++) {
                if (j == a) continue;
                if (j > 0 && !vf_s[j - 1]) continue;   // node 0 (agent) always w=1
                pc += fmaxf(uval + vb[j * HH + t], 0.f);
            }
            pool_s[t] = pc;
            int ic = min(max(start + am1, 0), TOTAL - 1);
            ctx_s[t] = ngh_ctx[ic * HH + t];
        }
        __syncthreads();
        for (int r = t; r < G3; r += HH) {
            const float* wr  = Wih + r * HH;
            const float* wr2 = Whh + r * HH;
            float a0 = 0.f, a1 = 0.f;
            for (int d = 0; d < HH; d++) { a0 += wr[d] * pool_s[d]; a1 += wr2[d] * ctx_s[d]; }
            gi_s[r] = a0 + bih[r];
            gh_s[r] = a1 + bhh[r];
        }
        __syncthreads();
        {
            float r = 1.f / (1.f + expf(-(gi_s[t] + gh_s[t])));
            float z = 1.f / (1.f + expf(-(gi_s[HH + t] + gh_s[HH + t])));
            float n = tanhf(gi_s[2 * HH + t] + r * gh_s[2 * HH + t]);
            acc += (1.f - z) * n + z * ctx_s[t];
        }
        __syncthreads();
    }
    out2[bp * HH + t] = acc;
}

extern "C" void kernel_launch(void* const* d_in, const int* in_sizes, int n_in,
                              void* d_out, int out_size, void* d_ws, size_t ws_size,
                              hipStream_t stream)
{
    const float* agent_ctx = (const float*)d_in[1];
    const float* ngh_pos   = (const float*)d_in[2];
    const float* ngh_ctx   = (const float*)d_in[3];
    const float* lanes     = (const float*)d_in[4];
    const float* lane_ctx  = (const float*)d_in[5];
    const int*   sse       = (const int*)d_in[7];
    const unsigned char* vn8 = (const unsigned char*)d_in[8];
    const int*   vn32      = (const int*)d_in[8];
    const float* Wmsg = (const float*)d_in[9];
    const float* bmsg = (const float*)d_in[10];
    const float* Wih  = (const float*)d_in[11];
    const float* Whh  = (const float*)d_in[12];
    const float* bih  = (const float*)d_in[13];
    const float* bhh  = (const float*)d_in[14];
    float* ws  = (float*)d_ws;
    float* out = (float*)d_out;

    k0_repack<<<dim3(129), dim3(256), 0, stream>>>(Wmsg, ws);
    k1_uv<<<dim3(704), dim3(256), 0, stream>>>(agent_ctx, ngh_pos, ngh_ctx, sse,
                                               bmsg, ws, ws);
    k3_gru<<<dim3(512), dim3(384), 0, stream>>>(ws + U_OFF, ws + V_OFF, ngh_ctx, sse,
                                                Wih, Whh, bih, bhh, ws + OS_OFF);
    k4_out<<<dim3(640), dim3(128), 0, stream>>>(lanes, ngh_pos, lane_ctx, sse, vn8, vn32,
                                                ws + U_OFF, ws + V_OFF,
                                                ws + OS_OFF, ngh_ctx,
                                                Wih, Whh, bih, bhh, out);
}

// Round 15
// 125.612 us; speedup vs baseline: 1.0535x; 1.0535x over previous
//
#include <hip/hip_runtime.h>
#include <hip/hip_bf16.h>
#include <math.h>

#define BB 64
#define PP 10
#define SS 64
#define KK 32
#define HH 128
#define NN 33          // KK+1
#define TOTAL (BB*KK)  // 2048
#define G3 384         // 3*HH

// workspace layout (in floats)
// W_msg repack: wpos[2][128] | wa4[32][128][4] | wj4[32][128][4]
#define WPOS_OFF 0
#define WA4_OFF  256
#define WJ4_OFF  (256 + 16384)
#define WT_SZ    33024
#define U_OFF  WT_SZ
#define UV_SZ  (BB*NN*HH)
#define V_OFF  (U_OFF + UV_SZ)
#define OS_OFF (V_OFF + UV_SZ)

// seq_start_end may arrive as int32 (x64 off) or int64 (x64 on).
__device__ inline void get_se(const int* __restrict__ sse, int b, int& start, int& endv) {
    if (sse[1] == 0) { start = sse[4 * b]; endv = sse[4 * b + 2]; }   // int64
    else             { start = sse[2 * b]; endv = sse[2 * b + 1]; }   // int32
}

// ---------------- K0: repack W_msg (128x258) ----------------
__global__ __launch_bounds__(256) void k0_repack(const float* __restrict__ Wmsg,
                                                 float* __restrict__ wt) {
    int idx = blockIdx.x * 256 + threadIdx.x;
    if (idx < 256) {
        int c = idx >> 7, h = idx & 127;
        wt[WPOS_OFF + idx] = Wmsg[h * 258 + c];
    } else if (idx < WT_SZ) {
        int j = idx - 256;
        int reg = j >> 14;            // 0 -> wa4, 1 -> wj4
        int jj = j & 16383;
        int c4 = jj >> 9, rem = jj & 511, h = rem >> 2, i = rem & 3;
        int col = (reg ? 130 : 2) + 4 * c4 + i;
        wt[256 + j] = Wmsg[h * 258 + col];
    }
}

// ---------------- K1: u[b,a,h], v[b,a,h] ----------------
// R13-validated: LDS-staged ctx rows, 704 blocks for latency hiding.
__global__ __launch_bounds__(256) void k1_uv(
    const float* __restrict__ agent_ctx, const float* __restrict__ ngh_pos,
    const float* __restrict__ ngh_ctx, const int* __restrict__ sse,
    const float* __restrict__ bmsg, const float* __restrict__ wt,
    float* __restrict__ ws)
{
    int b = blockIdx.x / 11, tile = blockIdx.x % 11;
    int a0 = tile * 3;                // 33 = 11 * 3
    int t = threadIdx.x;
    int h = t & 127, half = t >> 7;   // waves 0,1 -> u ; waves 2,3 -> v
    int start, endv;
    get_se(sse, b, start, endv);

    __shared__ __align__(16) float ctx_s[3][HH];   // 1.5 KB
    __shared__ float pxy_s[3][2];

    if (t < 96) {                     // stage 3 ctx rows, coalesced float4
        int i = t >> 5, c = t & 31;
        int a = a0 + i;
        const float* src;
        if (a == 0) src = agent_ctx + (size_t)b * HH;
        else {
            int ic = min(max(start + a - 1, 0), TOTAL - 1);
            src = ngh_ctx + (size_t)ic * HH;
        }
        ((float4*)&ctx_s[i][0])[c] = ((const float4*)src)[c];
    }
    if (t < 3) {
        int a = a0 + t;
        float px = 0.f, py = 0.f;
        if (a > 0) {
            int ic = min(max(start + a - 1, 0), TOTAL - 1);
            px = ngh_pos[ic * 2]; py = ngh_pos[ic * 2 + 1];
        }
        pxy_s[t][0] = px; pxy_s[t][1] = py;
    }
    __syncthreads();

    const float4* w4base = (const float4*)(wt + (half ? WJ4_OFF : WA4_OFF));
    float acc[3] = {0.f, 0.f, 0.f};
    for (int c4 = 0; c4 < 32; c4++) {
        float4 w4 = w4base[c4 * 128 + h];              // coalesced 16B/lane (L2)
        #pragma unroll
        for (int i = 0; i < 3; i++) {
            float4 cv = ((const float4*)&ctx_s[i][0])[c4];  // LDS broadcast, free
            acc[i] += w4.x * cv.x + w4.y * cv.y + w4.z * cv.z + w4.w * cv.w;
        }
    }
    float wp0 = wt[WPOS_OFF + h], wp1 = wt[WPOS_OFF + 128 + h];
    float bm = bmsg[h];
    float* uout = ws + U_OFF;
    float* vout = ws + V_OFF;
    #pragma unroll
    for (int i = 0; i < 3; i++) {
        int a = a0 + i;
        float pt = pxy_s[i][0] * wp0 + pxy_s[i][1] * wp1;
        if (half == 0) uout[(b * NN + a) * HH + h] = acc[i] - pt;
        else           vout[(b * NN + a) * HH + h] = acc[i] + pt + bm;
    }
}

// ---------------- K3: u/v -> pooled (in LDS) -> gi/gh -> GRU -> per-b sum ----
// R15: attack the per-node shfl serialization (common to ALL k3 variants'
// 40-90us floor): node loop unrolled x4, shuffles batched (8 independent
// ds-pipe ops pipelined instead of 2 dependent per node). Stage unrolled
// (loads issued before writes). u row 0 dropped (unused). hn overlaid on
// dead v_s. LDS 60.5 KB.
__global__ __launch_bounds__(384) void k3_gru(
    const float* __restrict__ ws_u, const float* __restrict__ ws_v,
    const float* __restrict__ ngh_ctx, const int* __restrict__ sse,
    const float* __restrict__ Wih, const float* __restrict__ Whh,
    const float* __restrict__ bih, const float* __restrict__ bhh,
    float* __restrict__ outsum)
{
    int b = blockIdx.x >> 3, hc = blockIdx.x & 7;
    int t = threadIdx.x;
    __shared__ __align__(16) float u_s[KK][HH];      // 16 KB; u rows 1..32 -> pooled
    __shared__ __align__(16) float v_s[NN][HH];      // 16.5 KB (hn overlaid later)
    __shared__ __align__(16) float ctx_s[KK][HH];    // 16 KB
    __shared__ float gi_s[KK][48];                   // 6 KB
    __shared__ float gh_s[KK][48];                   // 6 KB
    int start, endv;
    get_se(sse, b, start, endv);

    // ---- stage u(rows 1..32), v, ctx into LDS; explicit unroll for MLP ----
    {
        const float4* us = (const float4*)(ws_u + (size_t)b * NN * HH + HH); // skip row 0
        const float4* vs = (const float4*)(ws_v + (size_t)b * NN * HH);
        float4* ud = (float4*)&u_s[0][0];
        float4* vd = (float4*)&v_s[0][0];
        #pragma unroll
        for (int rep = 0; rep < 3; rep++) {
            int i = t + rep * 384;
            if (i < KK * 32) ud[i] = us[i];      // 1024 float4
            if (i < NN * 32) vd[i] = vs[i];      // 1056 float4
        }
        float4* cd = (float4*)&ctx_s[0][0];
        #pragma unroll
        for (int rep = 0; rep < 3; rep++) {
            int i = t + rep * 384;
            if (i < KK * 32) {
                int n = i >> 5, c = i & 31;
                int ic = min(max(start + n, 0), TOTAL - 1);
                cd[i] = ((const float4*)(ngh_ctx + (size_t)ic * HH))[c];
            }
        }
    }
    __syncthreads();

    // ---- pooled in-place: u_s[n][h] <- sum_{j != n+1} relu(u+v[j]) ----
    for (int it = t; it < KK * HH; it += 384) {
        int n = it >> 7, h = it & 127;
        float uval = u_s[n][h];
        float s = 0.f;
        #pragma unroll 11
        for (int j = 0; j < NN; j++) s += fmaxf(uval + v_s[j][h], 0.f);
        s -= fmaxf(uval + v_s[n + 1][h], 0.f);   // remove diagonal (a = n+1)
        u_s[n][h] = s;
    }
    __syncthreads();

    bool is_gh = (t >= 192);
    int r4 = is_gh ? (t - 192) : t;     // 0..191
    int row = r4 >> 2;                  // 0..47
    int q   = r4 & 3;                   // quarter of the 128-d dot
    int grow = (row >> 4) * HH + hc * 16 + (row & 15);

    // weights in rotated chunk order matching the LDS read rotation
    const float4* Wr = (const float4*)((is_gh ? Whh : Wih) + (size_t)grow * HH);
    float4 w[8];
    int cidx[8];
    #pragma unroll
    for (int s = 0; s < 8; s++) {
        int idx = (s + 2 * q) & 7;      // bank set (idx*4)%32: distinct per q
        cidx[s] = q * 8 + idx;
        w[s] = Wr[cidx[s]];
    }
    float bias = is_gh ? bhh[grow] : bih[grow];

    const float4* vecbase = is_gh ? (const float4*)&ctx_s[0][0]
                                  : (const float4*)&u_s[0][0];   // pooled rows
    for (int n0 = 0; n0 < KK; n0 += 4) {
        float d0 = 0.f, d1 = 0.f, d2 = 0.f, d3 = 0.f;
        #pragma unroll
        for (int s = 0; s < 8; s++) {
            float4 w_ = w[s];
            float4 v0 = vecbase[(n0 + 0) * 32 + cidx[s]];
            float4 v1 = vecbase[(n0 + 1) * 32 + cidx[s]];
            float4 v2 = vecbase[(n0 + 2) * 32 + cidx[s]];
            float4 v3 = vecbase[(n0 + 3) * 32 + cidx[s]];
            d0 += w_.x * v0.x + w_.y * v0.y + w_.z * v0.z + w_.w * v0.w;
            d1 += w_.x * v1.x + w_.y * v1.y + w_.z * v1.z + w_.w * v1.w;
            d2 += w_.x * v2.x + w_.y * v2.y + w_.z * v2.z + w_.w * v2.w;
            d3 += w_.x * v3.x + w_.y * v3.y + w_.z * v3.z + w_.w * v3.w;
        }
        // batched quarter-combine: 4 independent xor1, then 4 independent xor2
        float e0 = __shfl_xor(d0, 1), e1 = __shfl_xor(d1, 1),
              e2 = __shfl_xor(d2, 1), e3 = __shfl_xor(d3, 1);
        d0 += e0; d1 += e1; d2 += e2; d3 += e3;
        float f0 = __shfl_xor(d0, 2), f1 = __shfl_xor(d1, 2),
              f2 = __shfl_xor(d2, 2), f3 = __shfl_xor(d3, 2);
        d0 += f0; d1 += f1; d2 += f2; d3 += f3;
        if (q == 0) {
            if (is_gh) {
                gh_s[n0 + 0][row] = d0 + bias; gh_s[n0 + 1][row] = d1 + bias;
                gh_s[n0 + 2][row] = d2 + bias; gh_s[n0 + 3][row] = d3 + bias;
            } else {
                gi_s[n0 + 0][row] = d0 + bias; gi_s[n0 + 1][row] = d1 + bias;
                gi_s[n0 + 2][row] = d2 + bias; gi_s[n0 + 3][row] = d3 + bias;
            }
        }
    }
    __syncthreads();
    float* hn_p = &v_s[0][0];                      // v dead after pooled: reuse
    for (int it = t; it < KK * 16; it += 384) {    // 512 GRU items, parallel
        int n = it >> 4, h = it & 15;
        float ir = gi_s[n][h], iz = gi_s[n][16 + h], inn = gi_s[n][32 + h];
        float hr = gh_s[n][h], hz = gh_s[n][16 + h], hnn = gh_s[n][32 + h];
        float cval = ctx_s[n][hc * 16 + h];
        float r = 1.f / (1.f + expf(-(ir + hr)));
        float z = 1.f / (1.f + expf(-(iz + hz)));
        float nn = tanhf(inn + r * hnn);
        hn_p[it] = (1.f - z) * nn + z * cval;
    }
    __syncthreads();
    if (t < 16) {
        float s = 0.f;
        #pragma unroll
        for (int n = 0; n < KK; n++) s += hn_p[n * 16 + t];
        outsum[b * HH + hc * 16 + t] = s;
    }
}

// ---------------- K4: validity, output assembly, lane_recon, slow path ----------------
__global__ __launch_bounds__(128) void k4_out(
    const float* __restrict__ lanes_in, const float* __restrict__ ngh_pos,
    const float* __restrict__ lane_ctx, const int* __restrict__ sse,
    const unsigned char* __restrict__ vn8, const int* __restrict__ vn32,
    const float* __restrict__ ws_u, const float* __restrict__ ws_v,
    const float* __restrict__ outsum, const float* __restrict__ ngh_ctx,
    const float* __restrict__ Wih, const float* __restrict__ Whh,
    const float* __restrict__ bih, const float* __restrict__ bhh,
    float* __restrict__ out)
{
    int bp = blockIdx.x;
    int b = bp / PP;
    int t = threadIdx.x;
    __shared__ float lane_s[SS][2];
    __shared__ float mins[4][KK];
    __shared__ int vf_s[KK];
    __shared__ int nan_s, ninv_s;
    __shared__ float pool_s[HH], ctx_s[HH], gi_s[G3], gh_s[G3];

    if (t == 0) nan_s = 0;
    __syncthreads();
    {
        int s = t >> 1, c = t & 1;
        float v = lanes_in[(s * (BB * PP) + bp) * 2 + c];
        lane_s[s][c] = v;
        if (isnan(v)) atomicOr(&nan_s, 1);
    }
    __syncthreads();
    bool lnan = nan_s != 0;
    int start, endv;
    get_se(sse, b, start, endv);
    bool vnb = (vn8[b] != 0) || (vn32[b] != 0);
    {
        int k = t & 31, sh = t >> 5;
        int ic = min(max(start + k, 0), TOTAL - 1);
        float nx = ngh_pos[ic * 2], ny = ngh_pos[ic * 2 + 1];
        float m;
        if (lnan) m = nx * nx + ny * ny;
        else {
            m = 3.4e38f;
            for (int s = sh * 16; s < sh * 16 + 16; s++) {
                float dx = nx - lane_s[s][0], dy = ny - lane_s[s][1];
                m = fminf(m, dx * dx + dy * dy);
            }
        }
        mins[sh][k] = m;
    }
    __syncthreads();
    if (t < KK) {
        float m = fminf(fminf(mins[0][t], mins[1][t]), fminf(mins[2][t], mins[3][t]));
        bool mask = (start + t) < endv;
        bool valid = (m < 25.0f) && mask && vnb;
        vf_s[t] = valid ? 1 : 0;
    }
    __syncthreads();
    if (t == 0) {
        int c = 0;
        for (int k2 = 0; k2 < KK; k2++) c += 1 - vf_s[k2];
        ninv_s = c;
    }
    out[bp * HH + t] = lane_ctx[bp * HH + t];
    __syncthreads();

    float* out2 = out + BB * PP * HH;
    if (ninv_s == 0) {
        out2[bp * HH + t] = outsum[b * HH + t];
        return;
    }
    // slow path (correctness only; not hit on this data): pooled recomputed
    // directly from u/v with the validity mask (pooled no longer materialized).
    float acc = 0.f;
    const float* ub = ws_u + b * NN * HH;
    const float* vb = ws_v + b * NN * HH;
    for (int am1 = 0; am1 < KK; am1++) {
        if (!vf_s[am1]) continue;
        int a = am1 + 1;
        {
            float uval = ub[a * HH + t];
            float pc = 0.f;
            for (int j = 0; j < NN; j++) {
                if (j == a) continue;
                if (j > 0 && !vf_s[j - 1]) continue;   // node 0 (agent) always w=1
                pc += fmaxf(uval + vb[j * HH + t], 0.f);
            }
            pool_s[t] = pc;
            int ic = min(max(start + am1, 0), TOTAL - 1);
            ctx_s[t] = ngh_ctx[ic * HH + t];
        }
        __syncthreads();
        for (int r = t; r < G3; r += HH) {
            const float* wr  = Wih + r * HH;
            const float* wr2 = Whh + r * HH;
            float a0 = 0.f, a1 = 0.f;
            for (int d = 0; d < HH; d++) { a0 += wr[d] * pool_s[d]; a1 += wr2[d] * ctx_s[d]; }
            gi_s[r] = a0 + bih[r];
            gh_s[r] = a1 + bhh[r];
        }
        __syncthreads();
        {
            float r = 1.f / (1.f + expf(-(gi_s[t] + gh_s[t])));
            float z = 1.f / (1.f + expf(-(gi_s[HH + t] + gh_s[HH + t])));
            float n = tanhf(gi_s[2 * HH + t] + r * gh_s[2 * HH + t]);
            acc += (1.f - z) * n + z * ctx_s[t];
        }
        __syncthreads();
    }
    out2[bp * HH + t] = acc;
}

extern "C" void kernel_launch(void* const* d_in, const int* in_sizes, int n_in,
                              void* d_out, int out_size, void* d_ws, size_t ws_size,
                              hipStream_t stream)
{
    const float* agent_ctx = (const float*)d_in[1];
    const float* ngh_pos   = (const float*)d_in[2];
    const float* ngh_ctx   = (const float*)d_in[3];
    const float* lanes     = (const float*)d_in[4];
    const float* lane_ctx  = (const float*)d_in[5];
    const int*   sse       = (const int*)d_in[7];
    const unsigned char* vn8 = (const unsigned char*)d_in[8];
    const int*   vn32      = (const int*)d_in[8];
    const float* Wmsg = (const float*)d_in[9];
    const float* bmsg = (const float*)d_in[10];
    const float* Wih  = (const float*)d_in[11];
    const float* Whh  = (const float*)d_in[12];
    const float* bih  = (const float*)d_in[13];
    const float* bhh  = (const float*)d_in[14];
    float* ws  = (float*)d_ws;
    float* out = (float*)d_out;

    k0_repack<<<dim3(129), dim3(256), 0, stream>>>(Wmsg, ws);
    k1_uv<<<dim3(704), dim3(256), 0, stream>>>(agent_ctx, ngh_pos, ngh_ctx, sse,
                                               bmsg, ws, ws);
    k3_gru<<<dim3(512), dim3(384), 0, stream>>>(ws + U_OFF, ws + V_OFF, ngh_ctx, sse,
                                                Wih, Whh, bih, bhh, ws + OS_OFF);
    k4_out<<<dim3(640), dim3(128), 0, stream>>>(lanes, ngh_pos, lane_ctx, sse, vn8, vn32,
                                                ws + U_OFF, ws + V_OFF,
                                                ws + OS_OFF, ngh_ctx,
                                                Wih, Whh, bih, bhh, out);
}